// Round 8
// baseline (307.307 us; speedup 1.0000x reference)
//
#include <hip/hip_runtime.h>
#include <hip/hip_bf16.h>
#include <stdint.h>

// Problem constants
#define B_BATCH 32
#define M_SEQ   512
#define R_TOT   16384      // B*M
#define D_IN    1024
#define E_DIM   2048       // lmd*d
#define NCAT    384        // 256 (G*NC) + 8 (G) padded to 3*128
#define NVALID  264

typedef float  f32x4 __attribute__((ext_vector_type(4)));
typedef short  s16x8 __attribute__((ext_vector_type(8)));

__device__ __forceinline__ uint16_t f2bf(float f) {
  uint32_t u = __builtin_bit_cast(uint32_t, f);
  uint32_t r = (u + 0x7fffu + ((u >> 16) & 1u)) >> 16;
  return (uint16_t)r;
}
__device__ __forceinline__ float bf2f(uint16_t u) {
  return __builtin_bit_cast(float, (uint32_t)u << 16);
}

__device__ __forceinline__ f32x4 mfma_bf16(s16x8 a, s16x8 b, f32x4 c) {
  asm("v_mfma_f32_16x16x32_bf16 %0, %1, %2, %0" : "+v"(c) : "v"(a), "v"(b));
  return c;
}

typedef __attribute__((address_space(3))) void lds_void_t;
typedef const __attribute__((address_space(1))) void gbl_void_t;
__device__ __forceinline__ void async_load16(const void* g, void* l) {
  __builtin_amdgcn_global_load_lds((gbl_void_t*)g, (lds_void_t*)l, 16, 0, 0);
}

#define FENCE() __builtin_amdgcn_sched_barrier(0)
// pre-phase: barrier only; counted lgkm waits are compiler-derived from reg deps
#define PH_PRE_NL() do { FENCE(); __builtin_amdgcn_s_barrier(); FENCE(); \
                         __builtin_amdgcn_s_setprio(1); } while (0)
#define PH_POST() do { __builtin_amdgcn_s_setprio(0); FENCE(); \
                       __builtin_amdgcn_s_barrier(); FENCE(); } while (0)

// ---------------- prep kernels ----------------
__global__ void zero_buf(float* __restrict__ p, int n) {
  int i = blockIdx.x * blockDim.x + threadIdx.x;
  if (i < n) p[i] = 0.0f;
}

__global__ void cvt_bf16(const float* __restrict__ src, uint16_t* __restrict__ dst, int n) {
  int i = blockIdx.x * blockDim.x + threadIdx.x;
  if (i < n) dst[i] = f2bf(src[i]);
}

__global__ void build_wcat(const float* __restrict__ W1, const float* __restrict__ W2,
                           uint16_t* __restrict__ wcat) {
  int i = blockIdx.x * blockDim.x + threadIdx.x;
  if (i >= NCAT * E_DIM) return;
  int row = i >> 11, col = i & (E_DIM - 1);
  float v = 0.0f;
  if (row < 256) v = W1[i];
  else if (row < NVALID) v = W2[(row - 256) * E_DIM + col];
  wcat[i] = f2bf(v);
}

__global__ void build_bcat(const float* __restrict__ b1, const float* __restrict__ b2,
                           float* __restrict__ bcat) {
  int i = blockIdx.x * blockDim.x + threadIdx.x;
  if (i >= NCAT) return;
  float v = 0.0f;
  if (i < 256) v = b1[i];
  else if (i < NVALID) v = b2[i - 256];
  bcat[i] = v;
}

// ---------------- row L2-normalize -> bf16 ----------------
__global__ __launch_bounds__(256) void normalize_rows(const float* __restrict__ x,
                                                      uint16_t* __restrict__ xn) {
  const int r = blockIdx.x, tid = threadIdx.x;
  const float4* xr = (const float4*)(x + (size_t)r * D_IN);
  float4 v = xr[tid];
  float ss = v.x * v.x + v.y * v.y + v.z * v.z + v.w * v.w;
  #pragma unroll
  for (int m = 32; m; m >>= 1) ss += __shfl_xor(ss, m);
  __shared__ float wsum[4];
  if ((tid & 63) == 0) wsum[tid >> 6] = ss;
  __syncthreads();
  float tot = wsum[0] + wsum[1] + wsum[2] + wsum[3];
  float scale = 1.0f / fmaxf(sqrtf(tot), 1e-12f);
  uint16_t* o = xn + (size_t)r * D_IN + tid * 4;
  o[0] = f2bf(v.x * scale); o[1] = f2bf(v.y * scale);
  o[2] = f2bf(v.z * scale); o[3] = f2bf(v.w * scale);
}

// ---------------- 256x256 8-phase MFMA GEMM, one-phase-ahead read pipeline ----
// C[M,N] = A[M,K] @ B[N,K]^T + bias, bf16 out. 512 thr (8 waves 2Mx4N), BK=64,
// LDS [2 buf][A/B][2 half][128x64] = 128 KB, XOR-chunk swizzle. Frag ds_reads
// are issued INSIDE phase i's MFMA region for phase i+1 (drain hides under the
// matrix pipe; compiler derives counted lgkm waits from reg deps). vmcnt(4)
// moved to g4 pre-barrier (before cross-tile reads); tail peeled (vmcnt(0) at
// tile NT-2, no prefetch at NT-1). Epilogue staged via LDS for coalesced stores.
template <int KDIM>
__global__ __launch_bounds__(512, 2) void gemm256(
    const uint16_t* __restrict__ A, const uint16_t* __restrict__ B,
    const float* __restrict__ bias, uint16_t* __restrict__ C, int N) {
  __shared__ uint16_t lds[65536];
  constexpr int NT = KDIM / 64;
  const int tid = threadIdx.x;
  const int w = tid >> 6, lane = tid & 63;
  const int wr = w >> 2, wc = w & 3;
  const int bm = blockIdx.x, bn = blockIdx.y;

  const int srow = tid >> 3;
  const int scol = (((tid & 7) ^ (srow & 7)) << 3);
  const int l15 = lane & 15, l4 = lane >> 4, lx = lane & 7;
  const int ck0 = ((l4) ^ lx) << 4;
  const int ck1 = ((4 + l4) ^ lx) << 4;

  const int arow0 = bm * 256, brow0 = bn * 256;

  auto STAGE = [&](const uint16_t* __restrict__ M, int grow0, int tile,
                   int bufi, int mat, int half) {
    if (tile >= NT) return;
    const uint16_t* src = M + (size_t)(grow0 + half * 128 + srow) * KDIM + tile * 64 + scol;
    uint16_t* dst = lds + ((bufi * 2 + mat) * 2 + half) * 8192 + w * 512;
    async_load16(src, dst);
    async_load16(src + (size_t)64 * KDIM, dst + 4096);
  };
  auto LDA = [&](int bufi, int mi, int ckb) -> s16x8 {
    return *(const s16x8*)((const char*)(lds + ((bufi * 2 + 0) * 2 + wr) * 8192)
                           + (mi * 16 + l15) * 128 + ckb);
  };
  auto LDB = [&](int bufi, int ni, int ckb) -> s16x8 {
    return *(const s16x8*)((const char*)(lds + ((bufi * 2 + 1) * 2 + (wc >> 1)) * 8192)
                           + ((wc & 1) * 64 + ni * 16 + l15) * 128 + ckb);
  };

  f32x4 acc[8][4] = {};
  s16x8 aLo[4][2], aHi[4][2], bLo[2][2], bHi[2][2];

  // fragment read sets (consumed one phase after issue)
  auto R1 = [&](int buf) {   // aLo + bLo (12 reads) -> used by MM1/MM2 (aLo), MM1/MM3 (bLo)
    #pragma unroll
    for (int mi = 0; mi < 4; ++mi) { aLo[mi][0] = LDA(buf, mi, ck0); aLo[mi][1] = LDA(buf, mi, ck1); }
    #pragma unroll
    for (int ni = 0; ni < 2; ++ni) { bLo[ni][0] = LDB(buf, ni, ck0); bLo[ni][1] = LDB(buf, ni, ck1); }
  };
  auto R2 = [&](int buf) {   // bHi (4 reads) -> used by MM2/MM4
    #pragma unroll
    for (int j = 0; j < 2; ++j) { bHi[j][0] = LDB(buf, 2 + j, ck0); bHi[j][1] = LDB(buf, 2 + j, ck1); }
  };
  auto R3 = [&](int buf) {   // aHi (8 reads) -> used by MM3/MM4
    #pragma unroll
    for (int mi = 0; mi < 4; ++mi) { aHi[mi][0] = LDA(buf, 4 + mi, ck0); aHi[mi][1] = LDA(buf, 4 + mi, ck1); }
  };

  auto MM1 = [&] {
    #pragma unroll
    for (int kk = 0; kk < 2; ++kk)
      #pragma unroll
      for (int mi = 0; mi < 4; ++mi)
        #pragma unroll
        for (int ni = 0; ni < 2; ++ni)
          acc[mi][ni] = mfma_bf16(aLo[mi][kk], bLo[ni][kk], acc[mi][ni]);
  };
  auto MM2 = [&] {
    #pragma unroll
    for (int kk = 0; kk < 2; ++kk)
      #pragma unroll
      for (int mi = 0; mi < 4; ++mi)
        #pragma unroll
        for (int j = 0; j < 2; ++j)
          acc[mi][2 + j] = mfma_bf16(aLo[mi][kk], bHi[j][kk], acc[mi][2 + j]);
  };
  auto MM3 = [&] {
    #pragma unroll
    for (int kk = 0; kk < 2; ++kk)
      #pragma unroll
      for (int mi = 0; mi < 4; ++mi)
        #pragma unroll
        for (int ni = 0; ni < 2; ++ni)
          acc[4 + mi][ni] = mfma_bf16(aHi[mi][kk], bLo[ni][kk], acc[4 + mi][ni]);
  };
  auto MM4 = [&] {
    #pragma unroll
    for (int kk = 0; kk < 2; ++kk)
      #pragma unroll
      for (int mi = 0; mi < 4; ++mi)
        #pragma unroll
        for (int j = 0; j < 2; ++j)
          acc[4 + mi][2 + j] = mfma_bf16(aHi[mi][kk], bHi[j][kk], acc[4 + mi][2 + j]);
  };

// 4-phase group for tile T in buf H. VM0: drain-all at g4 (tail-1). FINAL: no prefetch.
#define GROUP(H, T, VM0, FINAL) do {                                           \
    STAGE(A, arow0, (T) + 1, (H) ^ 1, 0, 0);                                   \
    PH_PRE_NL(); R2(H); MM1(); PH_POST();                                      \
    STAGE(A, arow0, (T) + 1, (H) ^ 1, 0, 1);                                   \
    PH_PRE_NL(); R3(H); MM2(); PH_POST();                                      \
    STAGE(B, brow0, (T) + 2, (H), 1, 0);                                       \
    PH_PRE_NL(); MM3(); PH_POST();                                             \
    STAGE(B, brow0, (T) + 2, (H), 1, 1);                                       \
    FENCE();                                                                   \
    if (!(FINAL)) {                                                            \
      if (VM0) asm volatile("s_waitcnt vmcnt(0)" ::: "memory");                \
      else     asm volatile("s_waitcnt vmcnt(4)" ::: "memory");                \
    }                                                                          \
    __builtin_amdgcn_s_barrier(); FENCE();                                     \
    __builtin_amdgcn_s_setprio(1);                                             \
    if (!(FINAL)) R1((H) ^ 1);                                                 \
    MM4(); PH_POST();                                                          \
  } while (0)

  // prologue: tile0 fully, tile1 B-halves; prime R1(buf0)
  STAGE(A, arow0, 0, 0, 0, 0); STAGE(A, arow0, 0, 0, 0, 1);
  STAGE(B, brow0, 0, 0, 1, 0); STAGE(B, brow0, 0, 0, 1, 1);
  STAGE(B, brow0, 1, 1, 1, 0); STAGE(B, brow0, 1, 1, 1, 1);
  FENCE();
  asm volatile("s_waitcnt vmcnt(4)" ::: "memory");
  __builtin_amdgcn_s_barrier(); FENCE();
  R1(0);

  for (int i = 0; i < NT / 2 - 1; ++i) {
    GROUP(0, 2 * i, false, false);
    GROUP(1, 2 * i + 1, false, false);
  }
  GROUP(0, NT - 2, true, false);
  GROUP(1, NT - 1, false, true);
#undef GROUP

  asm volatile("s_nop 7\n\ts_nop 7\n\ts_nop 7" ::);  // MFMA->VALU hazard drain

  // ---- epilogue: stage C-tile in LDS (16B-granule XOR swizzle), then
  // fully-coalesced stores (each thread: 256 contiguous bytes, full 64B lines)
  const int lr0 = wr * 128 + l4 * 4;
  const int lc0 = wc * 64 + l15;
  #pragma unroll
  for (int ni = 0; ni < 4; ++ni) {
    const int col = lc0 + ni * 16;
    const float bv = bias[bn * 256 + col];
    const int c16 = col >> 3, c7 = col & 7;
    #pragma unroll
    for (int mi = 0; mi < 8; ++mi) {
      #pragma unroll
      for (int jj = 0; jj < 4; ++jj) {
        const int row = lr0 + mi * 16 + jj;
        lds[row * 256 + ((c16 ^ (row & 31)) << 3) + c7] = f2bf(acc[mi][ni][jj] + bv);
      }
    }
  }
  __syncthreads();
  {
    const int row = tid >> 1, ch = tid & 1;
    const int r31 = row & 31;
    uint16_t* dst = C + (size_t)(arow0 + row) * N + bn * 256 + ch * 128;
    #pragma unroll
    for (int q = 0; q < 8; ++q) {
      const int c16a = ch * 16 + 2 * q;
      s16x8 v0 = *(const s16x8*)&lds[row * 256 + ((c16a ^ r31) << 3)];
      s16x8 v1 = *(const s16x8*)&lds[row * 256 + (((c16a + 1) ^ r31) << 3)];
      *(s16x8*)(dst + q * 16) = v0;
      *(s16x8*)(dst + q * 16 + 8) = v1;
    }
  }
}

// ---------------- 128x128 MFMA GEMM (m97-style), used for logits GEMM ----------------
template <typename OutT>
__global__ __launch_bounds__(256, 2) void gemm_bt(
    const uint16_t* __restrict__ A, const uint16_t* __restrict__ B,
    const float* __restrict__ bias, OutT* __restrict__ C, int N, int K) {
  __shared__ __align__(16) uint16_t As[128 * 64];
  __shared__ __align__(16) uint16_t Bs[128 * 64];
  const int tid = threadIdx.x;
  const int w = tid >> 6, lane = tid & 63;
  const int wr = w >> 1, wc = w & 1;
  const int tm = blockIdx.x, tn = blockIdx.y;

  f32x4 acc[4][4] = {};

  const int lrow = lane >> 3;
  const int lk = (lane & 7) * 8;
  const size_t a_row0 = (size_t)tm * 128;
  const size_t b_row0 = (size_t)tn * 128;

  for (int k0 = 0; k0 < K; k0 += 64) {
    #pragma unroll
    for (int j = 0; j < 4; ++j) {
      const int c = w * 4 + j;
      const int row = c * 8 + lrow;
      async_load16(A + (a_row0 + row) * K + k0 + lk, (void*)(As + c * 512));
      async_load16(B + (b_row0 + row) * K + k0 + lk, (void*)(Bs + c * 512));
    }
    __syncthreads();
    #pragma unroll
    for (int kk = 0; kk < 2; ++kk) {
      const int krow = kk * 32 + (lane >> 4) * 8;
      s16x8 af[4], bfr[4];
      #pragma unroll
      for (int mi = 0; mi < 4; ++mi)
        af[mi] = *(const s16x8*)&As[(wr * 64 + mi * 16 + (lane & 15)) * 64 + krow];
      #pragma unroll
      for (int ni = 0; ni < 4; ++ni)
        bfr[ni] = *(const s16x8*)&Bs[(wc * 64 + ni * 16 + (lane & 15)) * 64 + krow];
      #pragma unroll
      for (int mi = 0; mi < 4; ++mi)
        #pragma unroll
        for (int ni = 0; ni < 4; ++ni)
          acc[mi][ni] = mfma_bf16(af[mi], bfr[ni], acc[mi][ni]);
    }
    __syncthreads();
  }
  asm volatile("s_nop 7\n\ts_nop 7\n\ts_nop 7" ::);

  const int rbase = wr * 64 + (lane >> 4) * 4;
  const int cbase = wc * 64 + (lane & 15);
  #pragma unroll
  for (int ni = 0; ni < 4; ++ni) {
    const int col = tn * 128 + cbase + ni * 16;
    const float bv = bias[col];
    #pragma unroll
    for (int mi = 0; mi < 4; ++mi) {
      #pragma unroll
      for (int jj = 0; jj < 4; ++jj) {
        const int row = tm * 128 + rbase + mi * 16 + jj;
        float v = acc[mi][ni][jj] + bv;
        if constexpr (sizeof(OutT) == 2) C[(size_t)row * N + col] = (OutT)f2bf(v);
        else                             C[(size_t)row * N + col] = v;
      }
    }
  }
}

// ---------------- fused softmax + partial accumulate ----------------
__global__ __launch_bounds__(256) void softmax_accum(
    const float* __restrict__ logits,   // R x 384 (0..255 = a1 logits, 256..263 = a2)
    const uint16_t* __restrict__ xe,    // R x 2048 bf16
    float* __restrict__ t1,             // 32 x 256
    float* __restrict__ sacc) {         // 32 x 32
  const int tid = threadIdx.x;
  const int r0 = blockIdx.x * 32;
  const int b = r0 >> 9;
  __shared__ float p1s[256];
  __shared__ float a2s[8];
  float t1_local = 0.0f, s_local = 0.0f;

  for (int rr = 0; rr < 32; ++rr) {
    const int r = r0 + rr;
    const float* lrow = logits + (size_t)r * NCAT;
    float lg = lrow[tid];
    float mx = lg;
    #pragma unroll
    for (int m = 16; m; m >>= 1) mx = fmaxf(mx, __shfl_xor(mx, m));
    float e = __expf(lg - mx);
    float sm = e;
    #pragma unroll
    for (int m = 16; m; m >>= 1) sm += __shfl_xor(sm, m);
    p1s[tid] = e / sm;
    if (tid < 8) {
      float l2 = lrow[256 + tid];
      float m2 = l2;
      #pragma unroll
      for (int m = 4; m; m >>= 1) m2 = fmaxf(m2, __shfl_xor(m2, m));
      float e2 = __expf(l2 - m2);
      float s2 = e2;
      #pragma unroll
      for (int m = 4; m; m >>= 1) s2 += __shfl_xor(s2, m);
      a2s[tid] = e2 / s2;
    }
    __syncthreads();
    const uint16_t* xr = xe + (size_t)r * E_DIM;
    float a = 0.0f;
    #pragma unroll
    for (int g = 0; g < 8; ++g) a += a2s[g] * bf2f(xr[g * 256 + tid]);
    t1_local += a;
    if (tid < 32) {
      float sa = 0.0f;
      #pragma unroll
      for (int g = 0; g < 8; ++g) sa += a2s[g] * p1s[g * 32 + tid];
      s_local += sa;
    }
    __syncthreads();
  }
  atomicAdd(&t1[b * 256 + tid], t1_local);
  if (tid < 32) atomicAdd(&sacc[b * 32 + tid], s_local);
}

// ---------------- finalize ----------------
__global__ __launch_bounds__(256) void finalize(const float* __restrict__ t1,
                                                const float* __restrict__ sacc,
                                                const float* __restrict__ centroid,
                                                float* __restrict__ out) {
  const int b = blockIdx.x, tid = threadIdx.x;
  float cs = 0.0f;
  #pragma unroll
  for (int k = 0; k < 32; ++k) cs += sacc[b * 32 + k] * centroid[k * 256 + tid];
  float v = (t1[b * 256 + tid] - cs) * (1.0f / (float)M_SEQ);
  float ss = v * v;
  #pragma unroll
  for (int m = 32; m; m >>= 1) ss += __shfl_xor(ss, m);
  __shared__ float wsum[4];
  if ((tid & 63) == 0) wsum[tid >> 6] = ss;
  __syncthreads();
  float tot = wsum[0] + wsum[1] + wsum[2] + wsum[3];
  out[b * 256 + tid] = v / fmaxf(sqrtf(tot), 1e-12f);
}

extern "C" void kernel_launch(void* const* d_in, const int* in_sizes, int n_in,
                              void* d_out, int out_size, void* d_ws, size_t ws_size,
                              hipStream_t stream) {
  const float* x        = (const float*)d_in[0];
  // d_in[1] = mask (unused by reference math)
  const float* We       = (const float*)d_in[2];
  const float* be       = (const float*)d_in[3];
  const float* W1       = (const float*)d_in[4];
  const float* b1       = (const float*)d_in[5];
  const float* W2       = (const float*)d_in[6];
  const float* b2       = (const float*)d_in[7];
  const float* centroid = (const float*)d_in[8];
  float* out = (float*)d_out;

  char* ws = (char*)d_ws;
  // workspace layout (bytes), total ~101.5 MB; logits aliases xn (stream-ordered safe)
  uint16_t* xe     = (uint16_t*)(ws + 0);          //  64 MB  R x 2048 bf16
  uint16_t* xn     = (uint16_t*)(ws + 67108864);   //  32 MB  R x 1024 bf16
  float*    logits = (float*)  (ws + 67108864);    //  24 MB  R x 384 f32 (aliases xn)
  uint16_t* webf   = (uint16_t*)(ws + 100663296);  //   4 MB  2048 x 1024 bf16
  uint16_t* wcat   = (uint16_t*)(ws + 104857600);  // 1.5 MB  384 x 2048 bf16
  float*    bcat   = (float*)  (ws + 106430464);   //  1.5 KB 384 f32
  float*    t1     = (float*)  (ws + 106432000);   //  32 KB  32 x 256
  float*    sacc   = (float*)  (ws + 106464768);   //   4 KB  32 x 32

  // prep
  zero_buf  <<<dim3(36),   256, 0, stream>>>(t1, 8192 + 1024);
  cvt_bf16  <<<dim3(8192), 256, 0, stream>>>(We, webf, E_DIM * D_IN);
  build_wcat<<<dim3(3072), 256, 0, stream>>>(W1, W2, wcat);
  build_bcat<<<dim3(2),    256, 0, stream>>>(b1, b2, bcat);

  // pipeline
  normalize_rows<<<dim3(R_TOT), 256, 0, stream>>>(x, xn);
  gemm256<D_IN><<<dim3(R_TOT / 256, E_DIM / 256), 512, 0, stream>>>(
      xn, webf, be, xe, E_DIM);
  gemm_bt<float><<<dim3(R_TOT / 128, NCAT / 128), 256, 0, stream>>>(
      xe, wcat, bcat, logits, NCAT, E_DIM);
  softmax_accum<<<dim3(R_TOT / 32), 256, 0, stream>>>(logits, xe, t1, sacc);
  finalize<<<dim3(B_BATCH), 256, 0, stream>>>(t1, sacc, centroid, out);
}

// Round 9
// 298.609 us; speedup vs baseline: 1.0291x; 1.0291x over previous
//
#include <hip/hip_runtime.h>
#include <hip/hip_bf16.h>
#include <stdint.h>

// Problem constants
#define B_BATCH 32
#define M_SEQ   512
#define R_TOT   16384      // B*M
#define D_IN    1024
#define E_DIM   2048       // lmd*d
#define NCAT    384        // 256 (G*NC) + 8 (G) padded to 3*128
#define NVALID  264

typedef float  f32x4 __attribute__((ext_vector_type(4)));
typedef short  s16x8 __attribute__((ext_vector_type(8)));

__device__ __forceinline__ uint16_t f2bf(float f) {
  uint32_t u = __builtin_bit_cast(uint32_t, f);
  uint32_t r = (u + 0x7fffu + ((u >> 16) & 1u)) >> 16;
  return (uint16_t)r;
}
__device__ __forceinline__ float bf2f(uint16_t u) {
  return __builtin_bit_cast(float, (uint32_t)u << 16);
}

// MFMA via BUILTIN (not inline asm): lets the compiler keep the accumulator
// native in AGPRs. The r5-r8 inline-asm "v"-constraint version forced
// v_accvgpr_read/write pairs around EVERY mfma (acc lives in AGPRs: reported
// VGPR_Count=60/128 < acc size) -> ~128 hidden VALU moves per phase,
// VALUBusy ~18%, MfmaUtil capped ~30% regardless of schedule.
__device__ __forceinline__ f32x4 mfma_bf16(s16x8 a, s16x8 b, f32x4 c) {
  return __builtin_amdgcn_mfma_f32_16x16x32_bf16(a, b, c, 0, 0, 0);
}

typedef __attribute__((address_space(3))) void lds_void_t;
typedef const __attribute__((address_space(1))) void gbl_void_t;
__device__ __forceinline__ void async_load16(const void* g, void* l) {
  __builtin_amdgcn_global_load_lds((gbl_void_t*)g, (lds_void_t*)l, 16, 0, 0);
}

#define FENCE() __builtin_amdgcn_sched_barrier(0)
// pre-phase: barrier only; counted lgkm waits are compiler-derived from reg deps
#define PH_PRE_NL() do { FENCE(); __builtin_amdgcn_s_barrier(); FENCE(); \
                         __builtin_amdgcn_s_setprio(1); } while (0)
#define PH_POST() do { __builtin_amdgcn_s_setprio(0); FENCE(); \
                       __builtin_amdgcn_s_barrier(); FENCE(); } while (0)

// ---------------- prep kernels ----------------
__global__ void zero_buf(float* __restrict__ p, int n) {
  int i = blockIdx.x * blockDim.x + threadIdx.x;
  if (i < n) p[i] = 0.0f;
}

__global__ void cvt_bf16(const float* __restrict__ src, uint16_t* __restrict__ dst, int n) {
  int i = blockIdx.x * blockDim.x + threadIdx.x;
  if (i < n) dst[i] = f2bf(src[i]);
}

__global__ void build_wcat(const float* __restrict__ W1, const float* __restrict__ W2,
                           uint16_t* __restrict__ wcat) {
  int i = blockIdx.x * blockDim.x + threadIdx.x;
  if (i >= NCAT * E_DIM) return;
  int row = i >> 11, col = i & (E_DIM - 1);
  float v = 0.0f;
  if (row < 256) v = W1[i];
  else if (row < NVALID) v = W2[(row - 256) * E_DIM + col];
  wcat[i] = f2bf(v);
}

__global__ void build_bcat(const float* __restrict__ b1, const float* __restrict__ b2,
                           float* __restrict__ bcat) {
  int i = blockIdx.x * blockDim.x + threadIdx.x;
  if (i >= NCAT) return;
  float v = 0.0f;
  if (i < 256) v = b1[i];
  else if (i < NVALID) v = b2[i - 256];
  bcat[i] = v;
}

// ---------------- row L2-normalize -> bf16 ----------------
__global__ __launch_bounds__(256) void normalize_rows(const float* __restrict__ x,
                                                      uint16_t* __restrict__ xn) {
  const int r = blockIdx.x, tid = threadIdx.x;
  const float4* xr = (const float4*)(x + (size_t)r * D_IN);
  float4 v = xr[tid];
  float ss = v.x * v.x + v.y * v.y + v.z * v.z + v.w * v.w;
  #pragma unroll
  for (int m = 32; m; m >>= 1) ss += __shfl_xor(ss, m);
  __shared__ float wsum[4];
  if ((tid & 63) == 0) wsum[tid >> 6] = ss;
  __syncthreads();
  float tot = wsum[0] + wsum[1] + wsum[2] + wsum[3];
  float scale = 1.0f / fmaxf(sqrtf(tot), 1e-12f);
  uint16_t* o = xn + (size_t)r * D_IN + tid * 4;
  o[0] = f2bf(v.x * scale); o[1] = f2bf(v.y * scale);
  o[2] = f2bf(v.z * scale); o[3] = f2bf(v.w * scale);
}

// ---------------- 256x256 8-phase MFMA GEMM, one-phase-ahead read pipeline ----
// C[M,N] = A[M,K] @ B[N,K]^T + bias, bf16 out. 512 thr (8 waves 2Mx4N), BK=64,
// LDS [2 buf][A/B][2 half][128x64] = 128 KB, XOR-chunk swizzle. Frag ds_reads
// are issued INSIDE phase i's MFMA region for phase i+1 (drain hides under the
// matrix pipe; compiler derives counted lgkm waits from reg deps). vmcnt(4)
// moved to g4 pre-barrier (before cross-tile reads); tail peeled (vmcnt(0) at
// tile NT-2, no prefetch at NT-1). Epilogue staged via LDS for coalesced stores.
template <int KDIM>
__global__ __launch_bounds__(512, 2) void gemm256(
    const uint16_t* __restrict__ A, const uint16_t* __restrict__ B,
    const float* __restrict__ bias, uint16_t* __restrict__ C, int N) {
  __shared__ uint16_t lds[65536];
  constexpr int NT = KDIM / 64;
  const int tid = threadIdx.x;
  const int w = tid >> 6, lane = tid & 63;
  const int wr = w >> 2, wc = w & 3;
  const int bm = blockIdx.x, bn = blockIdx.y;

  const int srow = tid >> 3;
  const int scol = (((tid & 7) ^ (srow & 7)) << 3);
  const int l15 = lane & 15, l4 = lane >> 4, lx = lane & 7;
  const int ck0 = ((l4) ^ lx) << 4;
  const int ck1 = ((4 + l4) ^ lx) << 4;

  const int arow0 = bm * 256, brow0 = bn * 256;

  auto STAGE = [&](const uint16_t* __restrict__ M, int grow0, int tile,
                   int bufi, int mat, int half) {
    if (tile >= NT) return;
    const uint16_t* src = M + (size_t)(grow0 + half * 128 + srow) * KDIM + tile * 64 + scol;
    uint16_t* dst = lds + ((bufi * 2 + mat) * 2 + half) * 8192 + w * 512;
    async_load16(src, dst);
    async_load16(src + (size_t)64 * KDIM, dst + 4096);
  };
  auto LDA = [&](int bufi, int mi, int ckb) -> s16x8 {
    return *(const s16x8*)((const char*)(lds + ((bufi * 2 + 0) * 2 + wr) * 8192)
                           + (mi * 16 + l15) * 128 + ckb);
  };
  auto LDB = [&](int bufi, int ni, int ckb) -> s16x8 {
    return *(const s16x8*)((const char*)(lds + ((bufi * 2 + 1) * 2 + (wc >> 1)) * 8192)
                           + ((wc & 1) * 64 + ni * 16 + l15) * 128 + ckb);
  };

  f32x4 acc[8][4] = {};
  s16x8 aLo[4][2], aHi[4][2], bLo[2][2], bHi[2][2];

  // fragment read sets (consumed one phase after issue)
  auto R1 = [&](int buf) {   // aLo + bLo (12 reads) -> used by MM1/MM2 (aLo), MM1/MM3 (bLo)
    #pragma unroll
    for (int mi = 0; mi < 4; ++mi) { aLo[mi][0] = LDA(buf, mi, ck0); aLo[mi][1] = LDA(buf, mi, ck1); }
    #pragma unroll
    for (int ni = 0; ni < 2; ++ni) { bLo[ni][0] = LDB(buf, ni, ck0); bLo[ni][1] = LDB(buf, ni, ck1); }
  };
  auto R2 = [&](int buf) {   // bHi (4 reads) -> used by MM2/MM4
    #pragma unroll
    for (int j = 0; j < 2; ++j) { bHi[j][0] = LDB(buf, 2 + j, ck0); bHi[j][1] = LDB(buf, 2 + j, ck1); }
  };
  auto R3 = [&](int buf) {   // aHi (8 reads) -> used by MM3/MM4
    #pragma unroll
    for (int mi = 0; mi < 4; ++mi) { aHi[mi][0] = LDA(buf, 4 + mi, ck0); aHi[mi][1] = LDA(buf, 4 + mi, ck1); }
  };

  auto MM1 = [&] {
    #pragma unroll
    for (int kk = 0; kk < 2; ++kk)
      #pragma unroll
      for (int mi = 0; mi < 4; ++mi)
        #pragma unroll
        for (int ni = 0; ni < 2; ++ni)
          acc[mi][ni] = mfma_bf16(aLo[mi][kk], bLo[ni][kk], acc[mi][ni]);
  };
  auto MM2 = [&] {
    #pragma unroll
    for (int kk = 0; kk < 2; ++kk)
      #pragma unroll
      for (int mi = 0; mi < 4; ++mi)
        #pragma unroll
        for (int j = 0; j < 2; ++j)
          acc[mi][2 + j] = mfma_bf16(aLo[mi][kk], bHi[j][kk], acc[mi][2 + j]);
  };
  auto MM3 = [&] {
    #pragma unroll
    for (int kk = 0; kk < 2; ++kk)
      #pragma unroll
      for (int mi = 0; mi < 4; ++mi)
        #pragma unroll
        for (int ni = 0; ni < 2; ++ni)
          acc[4 + mi][ni] = mfma_bf16(aHi[mi][kk], bLo[ni][kk], acc[4 + mi][ni]);
  };
  auto MM4 = [&] {
    #pragma unroll
    for (int kk = 0; kk < 2; ++kk)
      #pragma unroll
      for (int mi = 0; mi < 4; ++mi)
        #pragma unroll
        for (int j = 0; j < 2; ++j)
          acc[4 + mi][2 + j] = mfma_bf16(aHi[mi][kk], bHi[j][kk], acc[4 + mi][2 + j]);
  };

// 4-phase group for tile T in buf H. VM0: drain-all at g4 (tail-1). FINAL: no prefetch.
#define GROUP(H, T, VM0, FINAL) do {                                           \
    STAGE(A, arow0, (T) + 1, (H) ^ 1, 0, 0);                                   \
    PH_PRE_NL(); R2(H); MM1(); PH_POST();                                      \
    STAGE(A, arow0, (T) + 1, (H) ^ 1, 0, 1);                                   \
    PH_PRE_NL(); R3(H); MM2(); PH_POST();                                      \
    STAGE(B, brow0, (T) + 2, (H), 1, 0);                                       \
    PH_PRE_NL(); MM3(); PH_POST();                                             \
    STAGE(B, brow0, (T) + 2, (H), 1, 1);                                       \
    FENCE();                                                                   \
    if (!(FINAL)) {                                                            \
      if (VM0) asm volatile("s_waitcnt vmcnt(0)" ::: "memory");                \
      else     asm volatile("s_waitcnt vmcnt(4)" ::: "memory");                \
    }                                                                          \
    __builtin_amdgcn_s_barrier(); FENCE();                                     \
    __builtin_amdgcn_s_setprio(1);                                             \
    if (!(FINAL)) R1((H) ^ 1);                                                 \
    MM4(); PH_POST();                                                          \
  } while (0)

  // prologue: tile0 fully, tile1 B-halves; prime R1(buf0)
  STAGE(A, arow0, 0, 0, 0, 0); STAGE(A, arow0, 0, 0, 0, 1);
  STAGE(B, brow0, 0, 0, 1, 0); STAGE(B, brow0, 0, 0, 1, 1);
  STAGE(B, brow0, 1, 1, 1, 0); STAGE(B, brow0, 1, 1, 1, 1);
  FENCE();
  asm volatile("s_waitcnt vmcnt(4)" ::: "memory");
  __builtin_amdgcn_s_barrier(); FENCE();
  R1(0);

  for (int i = 0; i < NT / 2 - 1; ++i) {
    GROUP(0, 2 * i, false, false);
    GROUP(1, 2 * i + 1, false, false);
  }
  GROUP(0, NT - 2, true, false);
  GROUP(1, NT - 1, false, true);
#undef GROUP

  asm volatile("s_nop 7\n\ts_nop 7\n\ts_nop 7" ::);  // MFMA->VALU hazard drain

  // ---- epilogue: stage C-tile in LDS (16B-granule XOR swizzle), then
  // fully-coalesced stores (each thread: 256 contiguous bytes, full 64B lines)
  const int lr0 = wr * 128 + l4 * 4;
  const int lc0 = wc * 64 + l15;
  #pragma unroll
  for (int ni = 0; ni < 4; ++ni) {
    const int col = lc0 + ni * 16;
    const float bv = bias[bn * 256 + col];
    const int c16 = col >> 3, c7 = col & 7;
    #pragma unroll
    for (int mi = 0; mi < 8; ++mi) {
      #pragma unroll
      for (int jj = 0; jj < 4; ++jj) {
        const int row = lr0 + mi * 16 + jj;
        lds[row * 256 + ((c16 ^ (row & 31)) << 3) + c7] = f2bf(acc[mi][ni][jj] + bv);
      }
    }
  }
  __syncthreads();
  {
    const int row = tid >> 1, ch = tid & 1;
    const int r31 = row & 31;
    uint16_t* dst = C + (size_t)(arow0 + row) * N + bn * 256 + ch * 128;
    #pragma unroll
    for (int q = 0; q < 8; ++q) {
      const int c16a = ch * 16 + 2 * q;
      s16x8 v0 = *(const s16x8*)&lds[row * 256 + ((c16a ^ r31) << 3)];
      s16x8 v1 = *(const s16x8*)&lds[row * 256 + (((c16a + 1) ^ r31) << 3)];
      *(s16x8*)(dst + q * 16) = v0;
      *(s16x8*)(dst + q * 16 + 8) = v1;
    }
  }
}

// ---------------- 128x128 MFMA GEMM (m97-style), used for logits GEMM ----------------
template <typename OutT>
__global__ __launch_bounds__(256, 2) void gemm_bt(
    const uint16_t* __restrict__ A, const uint16_t* __restrict__ B,
    const float* __restrict__ bias, OutT* __restrict__ C, int N, int K) {
  __shared__ __align__(16) uint16_t As[128 * 64];
  __shared__ __align__(16) uint16_t Bs[128 * 64];
  const int tid = threadIdx.x;
  const int w = tid >> 6, lane = tid & 63;
  const int wr = w >> 1, wc = w & 1;
  const int tm = blockIdx.x, tn = blockIdx.y;

  f32x4 acc[4][4] = {};

  const int lrow = lane >> 3;
  const int lk = (lane & 7) * 8;
  const size_t a_row0 = (size_t)tm * 128;
  const size_t b_row0 = (size_t)tn * 128;

  for (int k0 = 0; k0 < K; k0 += 64) {
    #pragma unroll
    for (int j = 0; j < 4; ++j) {
      const int c = w * 4 + j;
      const int row = c * 8 + lrow;
      async_load16(A + (a_row0 + row) * K + k0 + lk, (void*)(As + c * 512));
      async_load16(B + (b_row0 + row) * K + k0 + lk, (void*)(Bs + c * 512));
    }
    __syncthreads();
    #pragma unroll
    for (int kk = 0; kk < 2; ++kk) {
      const int krow = kk * 32 + (lane >> 4) * 8;
      s16x8 af[4], bfr[4];
      #pragma unroll
      for (int mi = 0; mi < 4; ++mi)
        af[mi] = *(const s16x8*)&As[(wr * 64 + mi * 16 + (lane & 15)) * 64 + krow];
      #pragma unroll
      for (int ni = 0; ni < 4; ++ni)
        bfr[ni] = *(const s16x8*)&Bs[(wc * 64 + ni * 16 + (lane & 15)) * 64 + krow];
      #pragma unroll
      for (int mi = 0; mi < 4; ++mi)
        #pragma unroll
        for (int ni = 0; ni < 4; ++ni)
          acc[mi][ni] = mfma_bf16(af[mi], bfr[ni], acc[mi][ni]);
    }
    __syncthreads();
  }
  asm volatile("s_nop 7\n\ts_nop 7\n\ts_nop 7" ::);

  const int rbase = wr * 64 + (lane >> 4) * 4;
  const int cbase = wc * 64 + (lane & 15);
  #pragma unroll
  for (int ni = 0; ni < 4; ++ni) {
    const int col = tn * 128 + cbase + ni * 16;
    const float bv = bias[col];
    #pragma unroll
    for (int mi = 0; mi < 4; ++mi) {
      #pragma unroll
      for (int jj = 0; jj < 4; ++jj) {
        const int row = tm * 128 + rbase + mi * 16 + jj;
        float v = acc[mi][ni][jj] + bv;
        if constexpr (sizeof(OutT) == 2) C[(size_t)row * N + col] = (OutT)f2bf(v);
        else                             C[(size_t)row * N + col] = v;
      }
    }
  }
}

// ---------------- fused softmax + partial accumulate ----------------
__global__ __launch_bounds__(256) void softmax_accum(
    const float* __restrict__ logits,   // R x 384 (0..255 = a1 logits, 256..263 = a2)
    const uint16_t* __restrict__ xe,    // R x 2048 bf16
    float* __restrict__ t1,             // 32 x 256
    float* __restrict__ sacc) {         // 32 x 32
  const int tid = threadIdx.x;
  const int r0 = blockIdx.x * 32;
  const int b = r0 >> 9;
  __shared__ float p1s[256];
  __shared__ float a2s[8];
  float t1_local = 0.0f, s_local = 0.0f;

  for (int rr = 0; rr < 32; ++rr) {
    const int r = r0 + rr;
    const float* lrow = logits + (size_t)r * NCAT;
    float lg = lrow[tid];
    float mx = lg;
    #pragma unroll
    for (int m = 16; m; m >>= 1) mx = fmaxf(mx, __shfl_xor(mx, m));
    float e = __expf(lg - mx);
    float sm = e;
    #pragma unroll
    for (int m = 16; m; m >>= 1) sm += __shfl_xor(sm, m);
    p1s[tid] = e / sm;
    if (tid < 8) {
      float l2 = lrow[256 + tid];
      float m2 = l2;
      #pragma unroll
      for (int m = 4; m; m >>= 1) m2 = fmaxf(m2, __shfl_xor(m2, m));
      float e2 = __expf(l2 - m2);
      float s2 = e2;
      #pragma unroll
      for (int m = 4; m; m >>= 1) s2 += __shfl_xor(s2, m);
      a2s[tid] = e2 / s2;
    }
    __syncthreads();
    const uint16_t* xr = xe + (size_t)r * E_DIM;
    float a = 0.0f;
    #pragma unroll
    for (int g = 0; g < 8; ++g) a += a2s[g] * bf2f(xr[g * 256 + tid]);
    t1_local += a;
    if (tid < 32) {
      float sa = 0.0f;
      #pragma unroll
      for (int g = 0; g < 8; ++g) sa += a2s[g] * p1s[g * 32 + tid];
      s_local += sa;
    }
    __syncthreads();
  }
  atomicAdd(&t1[b * 256 + tid], t1_local);
  if (tid < 32) atomicAdd(&sacc[b * 32 + tid], s_local);
}

// ---------------- finalize ----------------
__global__ __launch_bounds__(256) void finalize(const float* __restrict__ t1,
                                                const float* __restrict__ sacc,
                                                const float* __restrict__ centroid,
                                                float* __restrict__ out) {
  const int b = blockIdx.x, tid = threadIdx.x;
  float cs = 0.0f;
  #pragma unroll
  for (int k = 0; k < 32; ++k) cs += sacc[b * 32 + k] * centroid[k * 256 + tid];
  float v = (t1[b * 256 + tid] - cs) * (1.0f / (float)M_SEQ);
  float ss = v * v;
  #pragma unroll
  for (int m = 32; m; m >>= 1) ss += __shfl_xor(ss, m);
  __shared__ float wsum[4];
  if ((tid & 63) == 0) wsum[tid >> 6] = ss;
  __syncthreads();
  float tot = wsum[0] + wsum[1] + wsum[2] + wsum[3];
  out[b * 256 + tid] = v / fmaxf(sqrtf(tot), 1e-12f);
}

extern "C" void kernel_launch(void* const* d_in, const int* in_sizes, int n_in,
                              void* d_out, int out_size, void* d_ws, size_t ws_size,
                              hipStream_t stream) {
  const float* x        = (const float*)d_in[0];
  // d_in[1] = mask (unused by reference math)
  const float* We       = (const float*)d_in[2];
  const float* be       = (const float*)d_in[3];
  const float* W1       = (const float*)d_in[4];
  const float* b1       = (const float*)d_in[5];
  const float* W2       = (const float*)d_in[6];
  const float* b2       = (const float*)d_in[7];
  const float* centroid = (const float*)d_in[8];
  float* out = (float*)d_out;

  char* ws = (char*)d_ws;
  // workspace layout (bytes), total ~101.5 MB; logits aliases xn (stream-ordered safe)
  uint16_t* xe     = (uint16_t*)(ws + 0);          //  64 MB  R x 2048 bf16
  uint16_t* xn     = (uint16_t*)(ws + 67108864);   //  32 MB  R x 1024 bf16
  float*    logits = (float*)  (ws + 67108864);    //  24 MB  R x 384 f32 (aliases xn)
  uint16_t* webf   = (uint16_t*)(ws + 100663296);  //   4 MB  2048 x 1024 bf16
  uint16_t* wcat   = (uint16_t*)(ws + 104857600);  // 1.5 MB  384 x 2048 bf16
  float*    bcat   = (float*)  (ws + 106430464);   //  1.5 KB 384 f32
  float*    t1     = (float*)  (ws + 106432000);   //  32 KB  32 x 256
  float*    sacc   = (float*)  (ws + 106464768);   //   4 KB  32 x 32

  // prep
  zero_buf  <<<dim3(36),   256, 0, stream>>>(t1, 8192 + 1024);
  cvt_bf16  <<<dim3(8192), 256, 0, stream>>>(We, webf, E_DIM * D_IN);
  build_wcat<<<dim3(3072), 256, 0, stream>>>(W1, W2, wcat);
  build_bcat<<<dim3(2),    256, 0, stream>>>(b1, b2, bcat);

  // pipeline
  normalize_rows<<<dim3(R_TOT), 256, 0, stream>>>(x, xn);
  gemm256<D_IN><<<dim3(R_TOT / 256, E_DIM / 256), 512, 0, stream>>>(
      xn, webf, be, xe, E_DIM);
  gemm_bt<float><<<dim3(R_TOT / 128, NCAT / 128), 256, 0, stream>>>(
      xe, wcat, bcat, logits, NCAT, E_DIM);
  softmax_accum<<<dim3(R_TOT / 32), 256, 0, stream>>>(logits, xe, t1, sacc);
  finalize<<<dim3(B_BATCH), 256, 0, stream>>>(t1, sacc, centroid, out);
}

// Round 11
// 282.858 us; speedup vs baseline: 1.0864x; 1.0557x over previous
//
#include <hip/hip_runtime.h>
#include <hip/hip_bf16.h>
#include <stdint.h>

// Problem constants
#define B_BATCH 32
#define M_SEQ   512
#define R_TOT   16384      // B*M
#define D_IN    1024
#define E_DIM   2048       // lmd*d
#define NCAT    384        // 256 (G*NC) + 8 (G) padded to 3*128
#define NVALID  264

typedef float  f32x4 __attribute__((ext_vector_type(4)));
typedef short  s16x8 __attribute__((ext_vector_type(8)));

__device__ __forceinline__ uint16_t f2bf(float f) {
  uint32_t u = __builtin_bit_cast(uint32_t, f);
  uint32_t r = (u + 0x7fffu + ((u >> 16) & 1u)) >> 16;
  return (uint16_t)r;
}
__device__ __forceinline__ float bf2f(uint16_t u) {
  return __builtin_bit_cast(float, (uint32_t)u << 16);
}

__device__ __forceinline__ f32x4 mfma_bf16(s16x8 a, s16x8 b, f32x4 c) {
  return __builtin_amdgcn_mfma_f32_16x16x32_bf16(a, b, c, 0, 0, 0);
}

typedef __attribute__((address_space(3))) void lds_void_t;
typedef const __attribute__((address_space(1))) void gbl_void_t;
__device__ __forceinline__ void async_load16(const void* g, void* l) {
  __builtin_amdgcn_global_load_lds((gbl_void_t*)g, (lds_void_t*)l, 16, 0, 0);
}

// NO sched_barrier(0) fences (m141: order-pinning defeats the compiler scheduler,
// 874->510 TF). Correctness carried by s_barrier + "memory"-clobber vmcnt asm +
// data-dep lgkm waits: read->use always precedes the overwriting STAGE by >=4
// barriers; acc chains prevent cross-tile MFMA sinking.
#define PH_A() do { __builtin_amdgcn_s_barrier(); \
                    __builtin_amdgcn_s_setprio(1); } while (0)
#define PH_B() do { __builtin_amdgcn_s_setprio(0); \
                    __builtin_amdgcn_s_barrier(); } while (0)

// ---------------- prep kernels ----------------
__global__ void zero_buf(float* __restrict__ p, int n) {
  int i = blockIdx.x * blockDim.x + threadIdx.x;
  if (i < n) p[i] = 0.0f;
}

__global__ void cvt_bf16(const float* __restrict__ src, uint16_t* __restrict__ dst, int n) {
  int i = blockIdx.x * blockDim.x + threadIdx.x;
  if (i < n) dst[i] = f2bf(src[i]);
}

__global__ void build_wcat(const float* __restrict__ W1, const float* __restrict__ W2,
                           uint16_t* __restrict__ wcat) {
  int i = blockIdx.x * blockDim.x + threadIdx.x;
  if (i >= NCAT * E_DIM) return;
  int row = i >> 11, col = i & (E_DIM - 1);
  float v = 0.0f;
  if (row < 256) v = W1[i];
  else if (row < NVALID) v = W2[(row - 256) * E_DIM + col];
  wcat[i] = f2bf(v);
}

__global__ void build_bcat(const float* __restrict__ b1, const float* __restrict__ b2,
                           float* __restrict__ bcat) {
  int i = blockIdx.x * blockDim.x + threadIdx.x;
  if (i >= NCAT) return;
  float v = 0.0f;
  if (i < 256) v = b1[i];
  else if (i < NVALID) v = b2[i - 256];
  bcat[i] = v;
}

// ---------------- row L2-normalize -> bf16 ----------------
__global__ __launch_bounds__(256) void normalize_rows(const float* __restrict__ x,
                                                      uint16_t* __restrict__ xn) {
  const int r = blockIdx.x, tid = threadIdx.x;
  const float4* xr = (const float4*)(x + (size_t)r * D_IN);
  float4 v = xr[tid];
  float ss = v.x * v.x + v.y * v.y + v.z * v.z + v.w * v.w;
  #pragma unroll
  for (int m = 32; m; m >>= 1) ss += __shfl_xor(ss, m);
  __shared__ float wsum[4];
  if ((tid & 63) == 0) wsum[tid >> 6] = ss;
  __syncthreads();
  float tot = wsum[0] + wsum[1] + wsum[2] + wsum[3];
  float scale = 1.0f / fmaxf(sqrtf(tot), 1e-12f);
  uint16_t* o = xn + (size_t)r * D_IN + tid * 4;
  o[0] = f2bf(v.x * scale); o[1] = f2bf(v.y * scale);
  o[2] = f2bf(v.z * scale); o[3] = f2bf(v.w * scale);
}

// ---------------- 256x256 8-phase MFMA GEMM, one-phase-ahead read pipeline ----
// Same schedule as r8/r9 but WITHOUT sched_barrier(0) pinning.
template <int KDIM>
__global__ __launch_bounds__(512, 2) void gemm256(
    const uint16_t* __restrict__ A, const uint16_t* __restrict__ B,
    const float* __restrict__ bias, uint16_t* __restrict__ C, int N) {
  __shared__ uint16_t lds[65536];
  constexpr int NT = KDIM / 64;
  const int tid = threadIdx.x;
  const int w = tid >> 6, lane = tid & 63;
  const int wr = w >> 2, wc = w & 3;
  const int bm = blockIdx.x, bn = blockIdx.y;

  const int srow = tid >> 3;
  const int scol = (((tid & 7) ^ (srow & 7)) << 3);
  const int l15 = lane & 15, l4 = lane >> 4, lx = lane & 7;
  const int ck0 = ((l4) ^ lx) << 4;
  const int ck1 = ((4 + l4) ^ lx) << 4;

  const int arow0 = bm * 256, brow0 = bn * 256;

  auto STAGE = [&](const uint16_t* __restrict__ M, int grow0, int tile,
                   int bufi, int mat, int half) {
    if (tile >= NT) return;
    const uint16_t* src = M + (size_t)(grow0 + half * 128 + srow) * KDIM + tile * 64 + scol;
    uint16_t* dst = lds + ((bufi * 2 + mat) * 2 + half) * 8192 + w * 512;
    async_load16(src, dst);
    async_load16(src + (size_t)64 * KDIM, dst + 4096);
  };
  auto LDA = [&](int bufi, int mi, int ckb) -> s16x8 {
    return *(const s16x8*)((const char*)(lds + ((bufi * 2 + 0) * 2 + wr) * 8192)
                           + (mi * 16 + l15) * 128 + ckb);
  };
  auto LDB = [&](int bufi, int ni, int ckb) -> s16x8 {
    return *(const s16x8*)((const char*)(lds + ((bufi * 2 + 1) * 2 + (wc >> 1)) * 8192)
                           + ((wc & 1) * 64 + ni * 16 + l15) * 128 + ckb);
  };

  f32x4 acc[8][4] = {};
  s16x8 aLo[4][2], aHi[4][2], bLo[2][2], bHi[2][2];

  auto R1 = [&](int buf) {
    #pragma unroll
    for (int mi = 0; mi < 4; ++mi) { aLo[mi][0] = LDA(buf, mi, ck0); aLo[mi][1] = LDA(buf, mi, ck1); }
    #pragma unroll
    for (int ni = 0; ni < 2; ++ni) { bLo[ni][0] = LDB(buf, ni, ck0); bLo[ni][1] = LDB(buf, ni, ck1); }
  };
  auto R2 = [&](int buf) {
    #pragma unroll
    for (int j = 0; j < 2; ++j) { bHi[j][0] = LDB(buf, 2 + j, ck0); bHi[j][1] = LDB(buf, 2 + j, ck1); }
  };
  auto R3 = [&](int buf) {
    #pragma unroll
    for (int mi = 0; mi < 4; ++mi) { aHi[mi][0] = LDA(buf, 4 + mi, ck0); aHi[mi][1] = LDA(buf, 4 + mi, ck1); }
  };

  auto MM1 = [&] {
    #pragma unroll
    for (int kk = 0; kk < 2; ++kk)
      #pragma unroll
      for (int mi = 0; mi < 4; ++mi)
        #pragma unroll
        for (int ni = 0; ni < 2; ++ni)
          acc[mi][ni] = mfma_bf16(aLo[mi][kk], bLo[ni][kk], acc[mi][ni]);
  };
  auto MM2 = [&] {
    #pragma unroll
    for (int kk = 0; kk < 2; ++kk)
      #pragma unroll
      for (int mi = 0; mi < 4; ++mi)
        #pragma unroll
        for (int j = 0; j < 2; ++j)
          acc[mi][2 + j] = mfma_bf16(aLo[mi][kk], bHi[j][kk], acc[mi][2 + j]);
  };
  auto MM3 = [&] {
    #pragma unroll
    for (int kk = 0; kk < 2; ++kk)
      #pragma unroll
      for (int mi = 0; mi < 4; ++mi)
        #pragma unroll
        for (int ni = 0; ni < 2; ++ni)
          acc[4 + mi][ni] = mfma_bf16(aHi[mi][kk], bLo[ni][kk], acc[4 + mi][ni]);
  };
  auto MM4 = [&] {
    #pragma unroll
    for (int kk = 0; kk < 2; ++kk)
      #pragma unroll
      for (int mi = 0; mi < 4; ++mi)
        #pragma unroll
        for (int j = 0; j < 2; ++j)
          acc[4 + mi][2 + j] = mfma_bf16(aHi[mi][kk], bHi[j][kk], acc[4 + mi][2 + j]);
  };

#define GROUP(H, T, VM0, FINAL) do {                                           \
    STAGE(A, arow0, (T) + 1, (H) ^ 1, 0, 0);                                   \
    PH_A(); R2(H); MM1(); PH_B();                                              \
    STAGE(A, arow0, (T) + 1, (H) ^ 1, 0, 1);                                   \
    PH_A(); R3(H); MM2(); PH_B();                                              \
    STAGE(B, brow0, (T) + 2, (H), 1, 0);                                       \
    PH_A(); MM3(); PH_B();                                                     \
    STAGE(B, brow0, (T) + 2, (H), 1, 1);                                       \
    if (!(FINAL)) {                                                            \
      if (VM0) asm volatile("s_waitcnt vmcnt(0)" ::: "memory");                \
      else     asm volatile("s_waitcnt vmcnt(4)" ::: "memory");                \
    }                                                                          \
    __builtin_amdgcn_s_barrier();                                              \
    __builtin_amdgcn_s_setprio(1);                                             \
    if (!(FINAL)) R1((H) ^ 1);                                                 \
    MM4(); PH_B();                                                             \
  } while (0)

  // prologue: tile0 fully, tile1 B-halves; prime R1(buf0)
  STAGE(A, arow0, 0, 0, 0, 0); STAGE(A, arow0, 0, 0, 0, 1);
  STAGE(B, brow0, 0, 0, 1, 0); STAGE(B, brow0, 0, 0, 1, 1);
  STAGE(B, brow0, 1, 1, 1, 0); STAGE(B, brow0, 1, 1, 1, 1);
  asm volatile("s_waitcnt vmcnt(4)" ::: "memory");
  __builtin_amdgcn_s_barrier();
  R1(0);

  for (int i = 0; i < NT / 2 - 1; ++i) {
    GROUP(0, 2 * i, false, false);
    GROUP(1, 2 * i + 1, false, false);
  }
  GROUP(0, NT - 2, true, false);
  GROUP(1, NT - 1, false, true);
#undef GROUP

  // ---- epilogue: stage C-tile in LDS (16B-granule XOR swizzle), then
  // fully-coalesced stores (each thread: 256 contiguous bytes, full 64B lines)
  const int lr0 = wr * 128 + l4 * 4;
  const int lc0 = wc * 64 + l15;
  #pragma unroll
  for (int ni = 0; ni < 4; ++ni) {
    const int col = lc0 + ni * 16;
    const float bv = bias[bn * 256 + col];
    const int c16 = col >> 3, c7 = col & 7;
    #pragma unroll
    for (int mi = 0; mi < 8; ++mi) {
      #pragma unroll
      for (int jj = 0; jj < 4; ++jj) {
        const int row = lr0 + mi * 16 + jj;
        lds[row * 256 + ((c16 ^ (row & 31)) << 3) + c7] = f2bf(acc[mi][ni][jj] + bv);
      }
    }
  }
  __syncthreads();
  {
    const int row = tid >> 1, ch = tid & 1;
    const int r31 = row & 31;
    uint16_t* dst = C + (size_t)(arow0 + row) * N + bn * 256 + ch * 128;
    #pragma unroll
    for (int q = 0; q < 8; ++q) {
      const int c16a = ch * 16 + 2 * q;
      s16x8 v0 = *(const s16x8*)&lds[row * 256 + ((c16a ^ r31) << 3)];
      s16x8 v1 = *(const s16x8*)&lds[row * 256 + (((c16a + 1) ^ r31) << 3)];
      *(s16x8*)(dst + q * 16) = v0;
      *(s16x8*)(dst + q * 16 + 8) = v1;
    }
  }
}

// ---------------- 128x128 MFMA GEMM (m97-style), used for logits GEMM ----------------
template <typename OutT>
__global__ __launch_bounds__(256, 2) void gemm_bt(
    const uint16_t* __restrict__ A, const uint16_t* __restrict__ B,
    const float* __restrict__ bias, OutT* __restrict__ C, int N, int K) {
  __shared__ __align__(16) uint16_t As[128 * 64];
  __shared__ __align__(16) uint16_t Bs[128 * 64];
  const int tid = threadIdx.x;
  const int w = tid >> 6, lane = tid & 63;
  const int wr = w >> 1, wc = w & 1;
  const int tm = blockIdx.x, tn = blockIdx.y;

  f32x4 acc[4][4] = {};

  const int lrow = lane >> 3;
  const int lk = (lane & 7) * 8;
  const size_t a_row0 = (size_t)tm * 128;
  const size_t b_row0 = (size_t)tn * 128;

  for (int k0 = 0; k0 < K; k0 += 64) {
    #pragma unroll
    for (int j = 0; j < 4; ++j) {
      const int c = w * 4 + j;
      const int row = c * 8 + lrow;
      async_load16(A + (a_row0 + row) * K + k0 + lk, (void*)(As + c * 512));
      async_load16(B + (b_row0 + row) * K + k0 + lk, (void*)(Bs + c * 512));
    }
    __syncthreads();
    #pragma unroll
    for (int kk = 0; kk < 2; ++kk) {
      const int krow = kk * 32 + (lane >> 4) * 8;
      s16x8 af[4], bfr[4];
      #pragma unroll
      for (int mi = 0; mi < 4; ++mi)
        af[mi] = *(const s16x8*)&As[(wr * 64 + mi * 16 + (lane & 15)) * 64 + krow];
      #pragma unroll
      for (int ni = 0; ni < 4; ++ni)
        bfr[ni] = *(const s16x8*)&Bs[(wc * 64 + ni * 16 + (lane & 15)) * 64 + krow];
      #pragma unroll
      for (int mi = 0; mi < 4; ++mi)
        #pragma unroll
        for (int ni = 0; ni < 4; ++ni)
          acc[mi][ni] = mfma_bf16(af[mi], bfr[ni], acc[mi][ni]);
    }
    __syncthreads();
  }

  const int rbase = wr * 64 + (lane >> 4) * 4;
  const int cbase = wc * 64 + (lane & 15);
  #pragma unroll
  for (int ni = 0; ni < 4; ++ni) {
    const int col = tn * 128 + cbase + ni * 16;
    const float bv = bias[col];
    #pragma unroll
    for (int mi = 0; mi < 4; ++mi) {
      #pragma unroll
      for (int jj = 0; jj < 4; ++jj) {
        const int row = tm * 128 + rbase + mi * 16 + jj;
        float v = acc[mi][ni][jj] + bv;
        if constexpr (sizeof(OutT) == 2) C[(size_t)row * N + col] = (OutT)f2bf(v);
        else                             C[(size_t)row * N + col] = v;
      }
    }
  }
}

// ---------------- fused softmax + partial accumulate (wave-per-row) ----------
// One wave processes one row per iteration; NO block barriers, no LDS.
// Lane l owns a1 cols 4l..4l+3 (group g = l>>3); a2 softmax replicated per lane.
// t1: lane l accumulates d = 4l..4l+3. S: group-reduce via shfl_xor 8/16/32.
__global__ __launch_bounds__(256) void softmax_accum(
    const float* __restrict__ logits,   // R x 384 (0..255 a1 logits, 256..263 a2)
    const uint16_t* __restrict__ xe,    // R x 2048 bf16
    float* __restrict__ t1,             // 32 x 256
    float* __restrict__ sacc) {         // 32 x 32
  const int tid = threadIdx.x;
  const int lane = tid & 63, wv = tid >> 6;
  const int r0 = blockIdx.x * 32 + wv * 8;
  const int b = (blockIdx.x * 32) >> 9;
  const int g = lane >> 3;
  float t1v[4] = {0.f, 0.f, 0.f, 0.f};
  float sv[4]  = {0.f, 0.f, 0.f, 0.f};

  for (int rr = 0; rr < 8; ++rr) {
    const int r = r0 + rr;
    const float* lrow = logits + (size_t)r * NCAT;
    float4 lg = *(const float4*)(lrow + 4 * lane);
    // softmax over 32 cols = 8-lane group x 4 elems
    float mx = fmaxf(fmaxf(lg.x, lg.y), fmaxf(lg.z, lg.w));
    mx = fmaxf(mx, __shfl_xor(mx, 1));
    mx = fmaxf(mx, __shfl_xor(mx, 2));
    mx = fmaxf(mx, __shfl_xor(mx, 4));
    float e0 = __expf(lg.x - mx), e1 = __expf(lg.y - mx);
    float e2 = __expf(lg.z - mx), e3 = __expf(lg.w - mx);
    float sm = e0 + e1 + e2 + e3;
    sm += __shfl_xor(sm, 1); sm += __shfl_xor(sm, 2); sm += __shfl_xor(sm, 4);
    const float inv = 1.0f / sm;
    // a2 softmax over 8 groups (replicated on every lane)
    float4 la = *(const float4*)(lrow + 256);
    float4 lb = *(const float4*)(lrow + 260);
    float a2w[8] = {la.x, la.y, la.z, la.w, lb.x, lb.y, lb.z, lb.w};
    float m2 = a2w[0];
    #pragma unroll
    for (int j = 1; j < 8; ++j) m2 = fmaxf(m2, a2w[j]);
    float s2 = 0.0f;
    #pragma unroll
    for (int j = 0; j < 8; ++j) { a2w[j] = __expf(a2w[j] - m2); s2 += a2w[j]; }
    const float i2 = 1.0f / s2;
    #pragma unroll
    for (int j = 0; j < 8; ++j) a2w[j] *= i2;
    // t1 accumulation: d = 4*lane + e
    const uint16_t* xr = xe + (size_t)r * E_DIM + 4 * lane;
    #pragma unroll
    for (int gg = 0; gg < 8; ++gg) {
      ushort4 xv = *(const ushort4*)(xr + gg * 256);
      t1v[0] += a2w[gg] * bf2f(xv.x);
      t1v[1] += a2w[gg] * bf2f(xv.y);
      t1v[2] += a2w[gg] * bf2f(xv.z);
      t1v[3] += a2w[gg] * bf2f(xv.w);
    }
    // S contribution: this lane's p1 entries (group g, k = 4*(lane&7)+e)
    const float wgt = a2w[g] * inv;
    sv[0] += wgt * e0; sv[1] += wgt * e1; sv[2] += wgt * e2; sv[3] += wgt * e3;
  }
  // reduce sv over groups (lanes sharing lane&7)
  #pragma unroll
  for (int e = 0; e < 4; ++e) {
    sv[e] += __shfl_xor(sv[e], 8);
    sv[e] += __shfl_xor(sv[e], 16);
    sv[e] += __shfl_xor(sv[e], 32);
  }
  #pragma unroll
  for (int e = 0; e < 4; ++e)
    atomicAdd(&t1[b * 256 + 4 * lane + e], t1v[e]);
  if (lane < 8) {
    #pragma unroll
    for (int e = 0; e < 4; ++e)
      atomicAdd(&sacc[b * 32 + 4 * lane + e], sv[e]);
  }
}

// ---------------- finalize ----------------
__global__ __launch_bounds__(256) void finalize(const float* __restrict__ t1,
                                                const float* __restrict__ sacc,
                                                const float* __restrict__ centroid,
                                                float* __restrict__ out) {
  const int b = blockIdx.x, tid = threadIdx.x;
  float cs = 0.0f;
  #pragma unroll
  for (int k = 0; k < 32; ++k) cs += sacc[b * 32 + k] * centroid[k * 256 + tid];
  float v = (t1[b * 256 + tid] - cs) * (1.0f / (float)M_SEQ);
  float ss = v * v;
  #pragma unroll
  for (int m = 32; m; m >>= 1) ss += __shfl_xor(ss, m);
  __shared__ float wsum[4];
  if ((tid & 63) == 0) wsum[tid >> 6] = ss;
  __syncthreads();
  float tot = wsum[0] + wsum[1] + wsum[2] + wsum[3];
  out[b * 256 + tid] = v / fmaxf(sqrtf(tot), 1e-12f);
}

extern "C" void kernel_launch(void* const* d_in, const int* in_sizes, int n_in,
                              void* d_out, int out_size, void* d_ws, size_t ws_size,
                              hipStream_t stream) {
  const float* x        = (const float*)d_in[0];
  // d_in[1] = mask (unused by reference math)
  const float* We       = (const float*)d_in[2];
  const float* be       = (const float*)d_in[3];
  const float* W1       = (const float*)d_in[4];
  const float* b1       = (const float*)d_in[5];
  const float* W2       = (const float*)d_in[6];
  const float* b2       = (const float*)d_in[7];
  const float* centroid = (const float*)d_in[8];
  float* out = (float*)d_out;

  char* ws = (char*)d_ws;
  // workspace layout (bytes), total ~101.5 MB; logits aliases xn (stream-ordered safe)
  uint16_t* xe     = (uint16_t*)(ws + 0);          //  64 MB  R x 2048 bf16
  uint16_t* xn     = (uint16_t*)(ws + 67108864);   //  32 MB  R x 1024 bf16
  float*    logits = (float*)  (ws + 67108864);    //  24 MB  R x 384 f32 (aliases xn)
  uint16_t* webf   = (uint16_t*)(ws + 100663296);  //   4 MB  2048 x 1024 bf16
  uint16_t* wcat   = (uint16_t*)(ws + 104857600);  // 1.5 MB  384 x 2048 bf16
  float*    bcat   = (float*)  (ws + 106430464);   //  1.5 KB 384 f32
  float*    t1     = (float*)  (ws + 106432000);   //  32 KB  32 x 256
  float*    sacc   = (float*)  (ws + 106464768);   //   4 KB  32 x 32

  // prep
  zero_buf  <<<dim3(36),   256, 0, stream>>>(t1, 8192 + 1024);
  cvt_bf16  <<<dim3(8192), 256, 0, stream>>>(We, webf, E_DIM * D_IN);
  build_wcat<<<dim3(3072), 256, 0, stream>>>(W1, W2, wcat);
  build_bcat<<<dim3(2),    256, 0, stream>>>(b1, b2, bcat);

  // pipeline
  normalize_rows<<<dim3(R_TOT), 256, 0, stream>>>(x, xn);
  gemm256<D_IN><<<dim3(R_TOT / 256, E_DIM / 256), 512, 0, stream>>>(
      xn, webf, be, xe, E_DIM);
  gemm_bt<float><<<dim3(R_TOT / 128, NCAT / 128), 256, 0, stream>>>(
      xe, wcat, bcat, logits, NCAT, E_DIM);
  softmax_accum<<<dim3(R_TOT / 32), 256, 0, stream>>>(logits, xe, t1, sacc);
  finalize<<<dim3(B_BATCH), 256, 0, stream>>>(t1, sacc, centroid, out);
}

// Round 12
// 274.935 us; speedup vs baseline: 1.1177x; 1.0288x over previous
//
#include <hip/hip_runtime.h>
#include <hip/hip_bf16.h>
#include <stdint.h>

// Problem constants
#define B_BATCH 32
#define M_SEQ   512
#define R_TOT   16384      // B*M
#define D_IN    1024
#define E_DIM   2048       // lmd*d
#define NCAT    384        // 256 (G*NC) + 8 (G) padded to 3*128
#define NVALID  264

typedef float  f32x4 __attribute__((ext_vector_type(4)));
typedef short  s16x8 __attribute__((ext_vector_type(8)));

__device__ __forceinline__ uint16_t f2bf(float f) {
  uint32_t u = __builtin_bit_cast(uint32_t, f);
  uint32_t r = (u + 0x7fffu + ((u >> 16) & 1u)) >> 16;
  return (uint16_t)r;
}
__device__ __forceinline__ float bf2f(uint16_t u) {
  return __builtin_bit_cast(float, (uint32_t)u << 16);
}

__device__ __forceinline__ f32x4 mfma_bf16(s16x8 a, s16x8 b, f32x4 c) {
  return __builtin_amdgcn_mfma_f32_16x16x32_bf16(a, b, c, 0, 0, 0);
}

typedef __attribute__((address_space(3))) void lds_void_t;
typedef const __attribute__((address_space(1))) void gbl_void_t;
__device__ __forceinline__ void async_load16(const void* g, void* l) {
  __builtin_amdgcn_global_load_lds((gbl_void_t*)g, (lds_void_t*)l, 16, 0, 0);
}

#define PH_A() do { __builtin_amdgcn_s_barrier(); \
                    __builtin_amdgcn_s_setprio(1); } while (0)
#define PH_B() do { __builtin_amdgcn_s_setprio(0); \
                    __builtin_amdgcn_s_barrier(); } while (0)

// ---------------- fused prep kernel (was 4 separate launches) ----------------
// grid 8192x256 covers E_DIM*D_IN = 2M elements exactly.
__global__ void prep_all(const float* __restrict__ We, uint16_t* __restrict__ webf,
                         const float* __restrict__ W1, const float* __restrict__ W2,
                         uint16_t* __restrict__ wcat,
                         const float* __restrict__ b1, const float* __restrict__ b2,
                         float* __restrict__ bcat, float* __restrict__ t1z) {
  int i = blockIdx.x * blockDim.x + threadIdx.x;
  webf[i] = f2bf(We[i]);
  if (i < NCAT * E_DIM) {
    int row = i >> 11, col = i & (E_DIM - 1);
    float v = 0.0f;
    if (row < 256) v = W1[i];
    else if (row < NVALID) v = W2[(row - 256) * E_DIM + col];
    wcat[i] = f2bf(v);
  }
  if (i < NCAT) {
    float v = 0.0f;
    if (i < 256) v = b1[i];
    else if (i < NVALID) v = b2[i - 256];
    bcat[i] = v;
  }
  if (i < 9216) t1z[i] = 0.0f;   // t1 (8192) + sacc (1024), contiguous
}

// ---------------- row L2-normalize -> bf16 ----------------
__global__ __launch_bounds__(256) void normalize_rows(const float* __restrict__ x,
                                                      uint16_t* __restrict__ xn) {
  const int r = blockIdx.x, tid = threadIdx.x;
  const float4* xr = (const float4*)(x + (size_t)r * D_IN);
  float4 v = xr[tid];
  float ss = v.x * v.x + v.y * v.y + v.z * v.z + v.w * v.w;
  #pragma unroll
  for (int m = 32; m; m >>= 1) ss += __shfl_xor(ss, m);
  __shared__ float wsum[4];
  if ((tid & 63) == 0) wsum[tid >> 6] = ss;
  __syncthreads();
  float tot = wsum[0] + wsum[1] + wsum[2] + wsum[3];
  float scale = 1.0f / fmaxf(sqrtf(tot), 1e-12f);
  uint16_t* o = xn + (size_t)r * D_IN + tid * 4;
  o[0] = f2bf(v.x * scale); o[1] = f2bf(v.y * scale);
  o[2] = f2bf(v.z * scale); o[3] = f2bf(v.w * scale);
}

// ---------------- 256x256 8-phase MFMA GEMM (unchanged from r11) ----------
template <int KDIM>
__global__ __launch_bounds__(512, 2) void gemm256(
    const uint16_t* __restrict__ A, const uint16_t* __restrict__ B,
    const float* __restrict__ bias, uint16_t* __restrict__ C, int N) {
  __shared__ uint16_t lds[65536];
  constexpr int NT = KDIM / 64;
  const int tid = threadIdx.x;
  const int w = tid >> 6, lane = tid & 63;
  const int wr = w >> 2, wc = w & 3;
  const int bm = blockIdx.x, bn = blockIdx.y;

  const int srow = tid >> 3;
  const int scol = (((tid & 7) ^ (srow & 7)) << 3);
  const int l15 = lane & 15, l4 = lane >> 4, lx = lane & 7;
  const int ck0 = ((l4) ^ lx) << 4;
  const int ck1 = ((4 + l4) ^ lx) << 4;

  const int arow0 = bm * 256, brow0 = bn * 256;

  auto STAGE = [&](const uint16_t* __restrict__ M, int grow0, int tile,
                   int bufi, int mat, int half) {
    if (tile >= NT) return;
    const uint16_t* src = M + (size_t)(grow0 + half * 128 + srow) * KDIM + tile * 64 + scol;
    uint16_t* dst = lds + ((bufi * 2 + mat) * 2 + half) * 8192 + w * 512;
    async_load16(src, dst);
    async_load16(src + (size_t)64 * KDIM, dst + 4096);
  };
  auto LDA = [&](int bufi, int mi, int ckb) -> s16x8 {
    return *(const s16x8*)((const char*)(lds + ((bufi * 2 + 0) * 2 + wr) * 8192)
                           + (mi * 16 + l15) * 128 + ckb);
  };
  auto LDB = [&](int bufi, int ni, int ckb) -> s16x8 {
    return *(const s16x8*)((const char*)(lds + ((bufi * 2 + 1) * 2 + (wc >> 1)) * 8192)
                           + ((wc & 1) * 64 + ni * 16 + l15) * 128 + ckb);
  };

  f32x4 acc[8][4] = {};
  s16x8 aLo[4][2], aHi[4][2], bLo[2][2], bHi[2][2];

  auto R1 = [&](int buf) {
    #pragma unroll
    for (int mi = 0; mi < 4; ++mi) { aLo[mi][0] = LDA(buf, mi, ck0); aLo[mi][1] = LDA(buf, mi, ck1); }
    #pragma unroll
    for (int ni = 0; ni < 2; ++ni) { bLo[ni][0] = LDB(buf, ni, ck0); bLo[ni][1] = LDB(buf, ni, ck1); }
  };
  auto R2 = [&](int buf) {
    #pragma unroll
    for (int j = 0; j < 2; ++j) { bHi[j][0] = LDB(buf, 2 + j, ck0); bHi[j][1] = LDB(buf, 2 + j, ck1); }
  };
  auto R3 = [&](int buf) {
    #pragma unroll
    for (int mi = 0; mi < 4; ++mi) { aHi[mi][0] = LDA(buf, 4 + mi, ck0); aHi[mi][1] = LDA(buf, 4 + mi, ck1); }
  };

  auto MM1 = [&] {
    #pragma unroll
    for (int kk = 0; kk < 2; ++kk)
      #pragma unroll
      for (int mi = 0; mi < 4; ++mi)
        #pragma unroll
        for (int ni = 0; ni < 2; ++ni)
          acc[mi][ni] = mfma_bf16(aLo[mi][kk], bLo[ni][kk], acc[mi][ni]);
  };
  auto MM2 = [&] {
    #pragma unroll
    for (int kk = 0; kk < 2; ++kk)
      #pragma unroll
      for (int mi = 0; mi < 4; ++mi)
        #pragma unroll
        for (int j = 0; j < 2; ++j)
          acc[mi][2 + j] = mfma_bf16(aLo[mi][kk], bHi[j][kk], acc[mi][2 + j]);
  };
  auto MM3 = [&] {
    #pragma unroll
    for (int kk = 0; kk < 2; ++kk)
      #pragma unroll
      for (int mi = 0; mi < 4; ++mi)
        #pragma unroll
        for (int ni = 0; ni < 2; ++ni)
          acc[4 + mi][ni] = mfma_bf16(aHi[mi][kk], bLo[ni][kk], acc[4 + mi][ni]);
  };
  auto MM4 = [&] {
    #pragma unroll
    for (int kk = 0; kk < 2; ++kk)
      #pragma unroll
      for (int mi = 0; mi < 4; ++mi)
        #pragma unroll
        for (int j = 0; j < 2; ++j)
          acc[4 + mi][2 + j] = mfma_bf16(aHi[mi][kk], bHi[j][kk], acc[4 + mi][2 + j]);
  };

#define GROUP(H, T, VM0, FINAL) do {                                           \
    STAGE(A, arow0, (T) + 1, (H) ^ 1, 0, 0);                                   \
    PH_A(); R2(H); MM1(); PH_B();                                              \
    STAGE(A, arow0, (T) + 1, (H) ^ 1, 0, 1);                                   \
    PH_A(); R3(H); MM2(); PH_B();                                              \
    STAGE(B, brow0, (T) + 2, (H), 1, 0);                                       \
    PH_A(); MM3(); PH_B();                                                     \
    STAGE(B, brow0, (T) + 2, (H), 1, 1);                                       \
    if (!(FINAL)) {                                                            \
      if (VM0) asm volatile("s_waitcnt vmcnt(0)" ::: "memory");                \
      else     asm volatile("s_waitcnt vmcnt(4)" ::: "memory");                \
    }                                                                          \
    __builtin_amdgcn_s_barrier();                                              \
    __builtin_amdgcn_s_setprio(1);                                             \
    if (!(FINAL)) R1((H) ^ 1);                                                 \
    MM4(); PH_B();                                                             \
  } while (0)

  STAGE(A, arow0, 0, 0, 0, 0); STAGE(A, arow0, 0, 0, 0, 1);
  STAGE(B, brow0, 0, 0, 1, 0); STAGE(B, brow0, 0, 0, 1, 1);
  STAGE(B, brow0, 1, 1, 1, 0); STAGE(B, brow0, 1, 1, 1, 1);
  asm volatile("s_waitcnt vmcnt(4)" ::: "memory");
  __builtin_amdgcn_s_barrier();
  R1(0);

  for (int i = 0; i < NT / 2 - 1; ++i) {
    GROUP(0, 2 * i, false, false);
    GROUP(1, 2 * i + 1, false, false);
  }
  GROUP(0, NT - 2, true, false);
  GROUP(1, NT - 1, false, true);
#undef GROUP

  // epilogue: stage C-tile in LDS (16B-granule XOR swizzle) -> coalesced stores
  const int lr0 = wr * 128 + l4 * 4;
  const int lc0 = wc * 64 + l15;
  #pragma unroll
  for (int ni = 0; ni < 4; ++ni) {
    const int col = lc0 + ni * 16;
    const float bv = bias[bn * 256 + col];
    const int c16 = col >> 3, c7 = col & 7;
    #pragma unroll
    for (int mi = 0; mi < 8; ++mi) {
      #pragma unroll
      for (int jj = 0; jj < 4; ++jj) {
        const int row = lr0 + mi * 16 + jj;
        lds[row * 256 + ((c16 ^ (row & 31)) << 3) + c7] = f2bf(acc[mi][ni][jj] + bv);
      }
    }
  }
  __syncthreads();
  {
    const int row = tid >> 1, ch = tid & 1;
    const int r31 = row & 31;
    uint16_t* dst = C + (size_t)(arow0 + row) * N + bn * 256 + ch * 128;
    #pragma unroll
    for (int q = 0; q < 8; ++q) {
      const int c16a = ch * 16 + 2 * q;
      s16x8 v0 = *(const s16x8*)&lds[row * 256 + ((c16a ^ r31) << 3)];
      s16x8 v1 = *(const s16x8*)&lds[row * 256 + (((c16a + 1) ^ r31) << 3)];
      *(s16x8*)(dst + q * 16) = v0;
      *(s16x8*)(dst + q * 16 + 8) = v1;
    }
  }
}

// ---------------- 128x128 MFMA GEMM (m97-style), used for logits GEMM --------
// launch_bounds(256,4): 4 blocks/CU co-resident (VGPR 60, LDS 32KB permit it).
// The (256,2) cap left GEMM2's 384-block grid at ~1.5 blocks/CU -> the 2-phase
// loop's stage+vmcnt+barrier stall (m233: ~72%) had no TLP to hide under.
template <typename OutT>
__global__ __launch_bounds__(256, 4) void gemm_bt(
    const uint16_t* __restrict__ A, const uint16_t* __restrict__ B,
    const float* __restrict__ bias, OutT* __restrict__ C, int N, int K) {
  __shared__ __align__(16) uint16_t As[128 * 64];
  __shared__ __align__(16) uint16_t Bs[128 * 64];
  const int tid = threadIdx.x;
  const int w = tid >> 6, lane = tid & 63;
  const int wr = w >> 1, wc = w & 1;
  const int tm = blockIdx.x, tn = blockIdx.y;

  f32x4 acc[4][4] = {};

  const int lrow = lane >> 3;
  const int lk = (lane & 7) * 8;
  const size_t a_row0 = (size_t)tm * 128;
  const size_t b_row0 = (size_t)tn * 128;

  for (int k0 = 0; k0 < K; k0 += 64) {
    #pragma unroll
    for (int j = 0; j < 4; ++j) {
      const int c = w * 4 + j;
      const int row = c * 8 + lrow;
      async_load16(A + (a_row0 + row) * K + k0 + lk, (void*)(As + c * 512));
      async_load16(B + (b_row0 + row) * K + k0 + lk, (void*)(Bs + c * 512));
    }
    __syncthreads();
    #pragma unroll
    for (int kk = 0; kk < 2; ++kk) {
      const int krow = kk * 32 + (lane >> 4) * 8;
      s16x8 af[4], bfr[4];
      #pragma unroll
      for (int mi = 0; mi < 4; ++mi)
        af[mi] = *(const s16x8*)&As[(wr * 64 + mi * 16 + (lane & 15)) * 64 + krow];
      #pragma unroll
      for (int ni = 0; ni < 4; ++ni)
        bfr[ni] = *(const s16x8*)&Bs[(wc * 64 + ni * 16 + (lane & 15)) * 64 + krow];
      #pragma unroll
      for (int mi = 0; mi < 4; ++mi)
        #pragma unroll
        for (int ni = 0; ni < 4; ++ni)
          acc[mi][ni] = mfma_bf16(af[mi], bfr[ni], acc[mi][ni]);
    }
    __syncthreads();
  }

  const int rbase = wr * 64 + (lane >> 4) * 4;
  const int cbase = wc * 64 + (lane & 15);
  #pragma unroll
  for (int ni = 0; ni < 4; ++ni) {
    const int col = tn * 128 + cbase + ni * 16;
    const float bv = bias[col];
    #pragma unroll
    for (int mi = 0; mi < 4; ++mi) {
      #pragma unroll
      for (int jj = 0; jj < 4; ++jj) {
        const int row = tm * 128 + rbase + mi * 16 + jj;
        float v = acc[mi][ni][jj] + bv;
        if constexpr (sizeof(OutT) == 2) C[(size_t)row * N + col] = (OutT)f2bf(v);
        else                             C[(size_t)row * N + col] = v;
      }
    }
  }
}

// ---------------- fused softmax + partial accumulate (wave-per-row) ----------
__global__ __launch_bounds__(256) void softmax_accum(
    const float* __restrict__ logits,   // R x 384 (0..255 a1 logits, 256..263 a2)
    const uint16_t* __restrict__ xe,    // R x 2048 bf16
    float* __restrict__ t1,             // 32 x 256
    float* __restrict__ sacc) {         // 32 x 32
  const int tid = threadIdx.x;
  const int lane = tid & 63, wv = tid >> 6;
  const int r0 = blockIdx.x * 32 + wv * 8;
  const int b = (blockIdx.x * 32) >> 9;
  const int g = lane >> 3;
  float t1v[4] = {0.f, 0.f, 0.f, 0.f};
  float sv[4]  = {0.f, 0.f, 0.f, 0.f};

  for (int rr = 0; rr < 8; ++rr) {
    const int r = r0 + rr;
    const float* lrow = logits + (size_t)r * NCAT;
    float4 lg = *(const float4*)(lrow + 4 * lane);
    float mx = fmaxf(fmaxf(lg.x, lg.y), fmaxf(lg.z, lg.w));
    mx = fmaxf(mx, __shfl_xor(mx, 1));
    mx = fmaxf(mx, __shfl_xor(mx, 2));
    mx = fmaxf(mx, __shfl_xor(mx, 4));
    float e0 = __expf(lg.x - mx), e1 = __expf(lg.y - mx);
    float e2 = __expf(lg.z - mx), e3 = __expf(lg.w - mx);
    float sm = e0 + e1 + e2 + e3;
    sm += __shfl_xor(sm, 1); sm += __shfl_xor(sm, 2); sm += __shfl_xor(sm, 4);
    const float inv = 1.0f / sm;
    float4 la = *(const float4*)(lrow + 256);
    float4 lb = *(const float4*)(lrow + 260);
    float a2w[8] = {la.x, la.y, la.z, la.w, lb.x, lb.y, lb.z, lb.w};
    float m2 = a2w[0];
    #pragma unroll
    for (int j = 1; j < 8; ++j) m2 = fmaxf(m2, a2w[j]);
    float s2 = 0.0f;
    #pragma unroll
    for (int j = 0; j < 8; ++j) { a2w[j] = __expf(a2w[j] - m2); s2 += a2w[j]; }
    const float i2 = 1.0f / s2;
    #pragma unroll
    for (int j = 0; j < 8; ++j) a2w[j] *= i2;
    const uint16_t* xr = xe + (size_t)r * E_DIM + 4 * lane;
    #pragma unroll
    for (int gg = 0; gg < 8; ++gg) {
      ushort4 xv = *(const ushort4*)(xr + gg * 256);
      t1v[0] += a2w[gg] * bf2f(xv.x);
      t1v[1] += a2w[gg] * bf2f(xv.y);
      t1v[2] += a2w[gg] * bf2f(xv.z);
      t1v[3] += a2w[gg] * bf2f(xv.w);
    }
    const float wgt = a2w[g] * inv;
    sv[0] += wgt * e0; sv[1] += wgt * e1; sv[2] += wgt * e2; sv[3] += wgt * e3;
  }
  #pragma unroll
  for (int e = 0; e < 4; ++e) {
    sv[e] += __shfl_xor(sv[e], 8);
    sv[e] += __shfl_xor(sv[e], 16);
    sv[e] += __shfl_xor(sv[e], 32);
  }
  #pragma unroll
  for (int e = 0; e < 4; ++e)
    atomicAdd(&t1[b * 256 + 4 * lane + e], t1v[e]);
  if (lane < 8) {
    #pragma unroll
    for (int e = 0; e < 4; ++e)
      atomicAdd(&sacc[b * 32 + 4 * lane + e], sv[e]);
  }
}

// ---------------- finalize ----------------
__global__ __launch_bounds__(256) void finalize(const float* __restrict__ t1,
                                                const float* __restrict__ sacc,
                                                const float* __restrict__ centroid,
                                                float* __restrict__ out) {
  const int b = blockIdx.x, tid = threadIdx.x;
  float cs = 0.0f;
  #pragma unroll
  for (int k = 0; k < 32; ++k) cs += sacc[b * 32 + k] * centroid[k * 256 + tid];
  float v = (t1[b * 256 + tid] - cs) * (1.0f / (float)M_SEQ);
  float ss = v * v;
  #pragma unroll
  for (int m = 32; m; m >>= 1) ss += __shfl_xor(ss, m);
  __shared__ float wsum[4];
  if ((tid & 63) == 0) wsum[tid >> 6] = ss;
  __syncthreads();
  float tot = wsum[0] + wsum[1] + wsum[2] + wsum[3];
  out[b * 256 + tid] = v / fmaxf(sqrtf(tot), 1e-12f);
}

extern "C" void kernel_launch(void* const* d_in, const int* in_sizes, int n_in,
                              void* d_out, int out_size, void* d_ws, size_t ws_size,
                              hipStream_t stream) {
  const float* x        = (const float*)d_in[0];
  // d_in[1] = mask (unused by reference math)
  const float* We       = (const float*)d_in[2];
  const float* be       = (const float*)d_in[3];
  const float* W1       = (const float*)d_in[4];
  const float* b1       = (const float*)d_in[5];
  const float* W2       = (const float*)d_in[6];
  const float* b2       = (const float*)d_in[7];
  const float* centroid = (const float*)d_in[8];
  float* out = (float*)d_out;

  char* ws = (char*)d_ws;
  // workspace layout (bytes), total ~101.5 MB; logits aliases xn (stream-ordered safe)
  uint16_t* xe     = (uint16_t*)(ws + 0);          //  64 MB  R x 2048 bf16
  uint16_t* xn     = (uint16_t*)(ws + 67108864);   //  32 MB  R x 1024 bf16
  float*    logits = (float*)  (ws + 67108864);    //  24 MB  R x 384 f32 (aliases xn)
  uint16_t* webf   = (uint16_t*)(ws + 100663296);  //   4 MB  2048 x 1024 bf16
  uint16_t* wcat   = (uint16_t*)(ws + 104857600);  // 1.5 MB  384 x 2048 bf16
  float*    bcat   = (float*)  (ws + 106430464);   //  1.5 KB 384 f32
  float*    t1     = (float*)  (ws + 106432000);   //  32 KB  32 x 256
  float*    sacc   = (float*)  (ws + 106464768);   //   4 KB  32 x 32

  // prep (single fused kernel)
  prep_all<<<dim3(8192), 256, 0, stream>>>(We, webf, W1, W2, wcat, b1, b2, bcat, t1);

  // pipeline
  normalize_rows<<<dim3(R_TOT), 256, 0, stream>>>(x, xn);
  gemm256<D_IN><<<dim3(R_TOT / 256, E_DIM / 256), 512, 0, stream>>>(
      xn, webf, be, xe, E_DIM);
  gemm_bt<float><<<dim3(R_TOT / 128, NCAT / 128), 256, 0, stream>>>(
      xe, wcat, bcat, logits, NCAT, E_DIM);
  softmax_accum<<<dim3(R_TOT / 32), 256, 0, stream>>>(logits, xe, t1, sacc);
  finalize<<<dim3(B_BATCH), 256, 0, stream>>>(t1, sacc, centroid, out);
}